// Round 1
// baseline (439.869 us; speedup 1.0000x reference)
//
#include <hip/hip_runtime.h>

// EdgeEmbedding: out[i,:] = edge_type_embedding[data[i],:] + segsum(attr_table[flat_attr_ids], attr_seg_ids)[data[i],:]
// N=1e6 edges, D=256, NUM_TYPES=1000, TOTAL_ATTRS=50k, ATTR_NUM=200k. All f32, indices int32.

#define EE_D        256
#define EE_D4       64          // D / 4 floats per float4
#define EE_NTYPES   1000

// Phase 0: comb[t][d] = edge_type_embedding[t][d]   (1000*256 floats = 1 MB in d_ws)
__global__ void ee_init_comb(const float4* __restrict__ ete, float4* __restrict__ comb) {
    int i = blockIdx.x * blockDim.x + threadIdx.x;
    if (i < EE_NTYPES * EE_D4) comb[i] = ete[i];
}

// Phase 1: comb[seg[a]][:] += attr_table[ids[a]][:]  via f32 atomics.
// One wave per attr row: 64 lanes x float4 = 256 floats.
__global__ void ee_seg_scatter(const float4* __restrict__ attr,
                               const int* __restrict__ ids,
                               const int* __restrict__ segs,
                               float* __restrict__ comb, int na) {
    int gid  = blockIdx.x * blockDim.x + threadIdx.x;
    int wave = gid >> 6;
    int lane = gid & 63;
    int nw   = (gridDim.x * blockDim.x) >> 6;
    for (int a = wave; a < na; a += nw) {
        int aid = ids[a];
        int seg = segs[a];
        float4 v = attr[(size_t)aid * EE_D4 + lane];
        float* dst = comb + (size_t)seg * EE_D + lane * 4;
        atomicAdd(dst + 0, v.x);
        atomicAdd(dst + 1, v.y);
        atomicAdd(dst + 2, v.z);
        atomicAdd(dst + 3, v.w);
    }
}

// Phase 2: out[r][:] = comb[data[r]][:].  One wave per row; 64 lanes x float4
// = one fully-coalesced 1 KB store per row. comb (1 MB) lives in L2/L3.
__global__ void ee_gather_out(const int* __restrict__ data,
                              const float4* __restrict__ comb,
                              float4* __restrict__ out, int n) {
    int gid  = blockIdx.x * blockDim.x + threadIdx.x;
    int wave = gid >> 6;
    int lane = gid & 63;
    int nw   = (gridDim.x * blockDim.x) >> 6;
    for (int r = wave; r < n; r += nw) {
        int t = data[r];                       // wave-uniform broadcast load
        out[(size_t)r * EE_D4 + lane] = comb[(size_t)t * EE_D4 + lane];
    }
}

extern "C" void kernel_launch(void* const* d_in, const int* in_sizes, int n_in,
                              void* d_out, int out_size, void* d_ws, size_t ws_size,
                              hipStream_t stream) {
    const int*   data          = (const int*)d_in[0];
    const float* attr_table    = (const float*)d_in[1];
    const float* ete           = (const float*)d_in[2];
    const int*   flat_attr_ids = (const int*)d_in[3];
    const int*   attr_seg_ids  = (const int*)d_in[4];
    float* comb = (float*)d_ws;                 // 1000*256 f32 = 1,024,000 B scratch
    float* out  = (float*)d_out;

    int N  = in_sizes[0];   // 1,000,000 edges
    int TA = in_sizes[3];   // 50,000 ragged attrs

    // Phase 0: seed combined table with edge-type embeddings (overwrites ws fully).
    ee_init_comb<<<(EE_NTYPES * EE_D4 + 255) / 256, 256, 0, stream>>>(
        (const float4*)ete, (float4*)comb);

    // Phase 1: segment-sum of gathered attr rows (atomic scatter-add).
    ee_seg_scatter<<<1024, 256, 0, stream>>>(
        (const float4*)attr_table, flat_attr_ids, attr_seg_ids, comb, TA);

    // Phase 2: 1M-row gather + streaming write (the bandwidth-bound phase).
    ee_gather_out<<<2048, 256, 0, stream>>>(
        data, (const float4*)comb, (float4*)out, N);
}

// Round 3
// 258.254 us; speedup vs baseline: 1.7032x; 1.7032x over previous
//
#include <hip/hip_runtime.h>

// EdgeEmbedding: out[i,:] = ete[data[i],:] + segsum(attr_table[flat_attr_ids], attr_seg_ids)[data[i],:]
// N=1e6, D=256, NUM_TYPES=1000, TOTAL_ATTRS=50k, ATTR_NUM=200k. All f32, idx int32.

#define EE_D   256
#define EE_D4  64          // float4s per row
#define EE_NT  1000

typedef float fvec4 __attribute__((ext_vector_type(4)));   // native vec: OK for nontemporal builtins

// Phase A (fused 0+1): one block per type t. 4 waves scan the (seg,id) list with
// coalesced 64-wide loads; ballot finds matches; fvec4 per-lane accumulators;
// LDS-combine; add ete[t]; single non-atomic write of comb[t]. Deterministic.
__global__ __launch_bounds__(256) void ee_build_comb(
        const fvec4* __restrict__ ete,
        const fvec4* __restrict__ attr,
        const int* __restrict__ ids,
        const int* __restrict__ segs,
        fvec4* __restrict__ comb, int na) {
    const int t    = blockIdx.x;
    const int tid  = threadIdx.x;
    const int wave = tid >> 6;
    const int lane = tid & 63;

    fvec4 acc = (fvec4)0.f;

    for (int base = wave * 64; base < na; base += 256) {
        int a = base + lane;
        int s = -1, id = 0;
        if (a < na) { s = segs[a]; id = ids[a]; }       // coalesced 256B loads
        unsigned long long m = __ballot(s == t);
        while (m) {                                      // ~0.06 matches / iter
            int j = __ffsll((long long)m) - 1;
            m &= m - 1;
            int aid = __shfl(id, j);
            acc += attr[(size_t)aid * EE_D4 + lane];     // 1KB coalesced row read
        }
    }

    __shared__ fvec4 red[4][64];
    red[wave][lane] = acc;
    __syncthreads();
    if (wave == 0) {
        fvec4 r = red[0][lane];
        #pragma unroll
        for (int w = 1; w < 4; ++w) r += red[w][lane];
        r += ete[(size_t)t * EE_D4 + lane];
        comb[(size_t)t * EE_D4 + lane] = r;
    }
}

// Phase B: out[r][:] = comb[data[r]][:]. Each wave handles 64-row chunks:
// one coalesced load of 64 indices, then shfl-broadcast per row so the
// per-row chain is just (shfl -> comb L2 load -> 1KB coalesced NT store).
__global__ __launch_bounds__(256) void ee_gather_out(
        const int* __restrict__ data,
        const fvec4* __restrict__ comb,
        fvec4* __restrict__ out, int n) {
    const int gid  = blockIdx.x * blockDim.x + threadIdx.x;
    const int wave = gid >> 6;
    const int lane = gid & 63;
    const int nw   = (gridDim.x * blockDim.x) >> 6;

    for (int base = wave * 64; base < n; base += nw * 64) {
        int r = base + lane;
        int idx = (r < n) ? data[r] : 0;                 // coalesced 256B load
        int lim = n - base;
        if (lim >= 64) {
            #pragma unroll 4
            for (int j = 0; j < 64; ++j) {
                int t = __shfl(idx, j);
                fvec4 v = comb[(size_t)t * EE_D4 + lane];
                __builtin_nontemporal_store(v, &out[(size_t)(base + j) * EE_D4 + lane]);
            }
        } else {
            for (int j = 0; j < lim; ++j) {
                int t = __shfl(idx, j);
                fvec4 v = comb[(size_t)t * EE_D4 + lane];
                __builtin_nontemporal_store(v, &out[(size_t)(base + j) * EE_D4 + lane]);
            }
        }
    }
}

extern "C" void kernel_launch(void* const* d_in, const int* in_sizes, int n_in,
                              void* d_out, int out_size, void* d_ws, size_t ws_size,
                              hipStream_t stream) {
    const int*   data          = (const int*)d_in[0];
    const float* attr_table    = (const float*)d_in[1];
    const float* ete           = (const float*)d_in[2];
    const int*   flat_attr_ids = (const int*)d_in[3];
    const int*   attr_seg_ids  = (const int*)d_in[4];
    fvec4* comb = (fvec4*)d_ws;                    // 1000*256 f32 = 1 MB scratch
    int N  = in_sizes[0];                          // 1,000,000 edges
    int TA = in_sizes[3];                          // 50,000 ragged attrs

    ee_build_comb<<<EE_NT, 256, 0, stream>>>(
        (const fvec4*)ete, (const fvec4*)attr_table,
        flat_attr_ids, attr_seg_ids, comb, TA);

    ee_gather_out<<<2048, 256, 0, stream>>>(
        data, comb, (fvec4*)d_out, N);
}

// Round 4
// 256.561 us; speedup vs baseline: 1.7145x; 1.0066x over previous
//
#include <hip/hip_runtime.h>

// EdgeEmbedding: out[i,:] = ete[data[i],:] + segsum(attr_table[flat_attr_ids], attr_seg_ids)[data[i],:]
// N=1e6, D=256, NUM_TYPES=1000, TOTAL_ATTRS=50k, ATTR_NUM=200k. All f32, idx int32.

#define EE_D   256
#define EE_D4  64          // float4s per row
#define EE_NT  1000
#define EE_K   4           // types per build block

typedef float fvec4 __attribute__((ext_vector_type(4)));

// Phase A: one block per EE_K types. 4 waves scan the (seg,id) list with
// coalesced 64-wide loads; one ballot per type; fvec4 per-lane accumulators;
// LDS-combine (wave k reduces type k); add ete; non-atomic comb write.
__global__ __launch_bounds__(256) void ee_build_comb(
        const fvec4* __restrict__ ete,
        const fvec4* __restrict__ attr,
        const int* __restrict__ ids,
        const int* __restrict__ segs,
        fvec4* __restrict__ comb, int na) {
    const int t0   = blockIdx.x * EE_K;
    const int tid  = threadIdx.x;
    const int wave = tid >> 6;
    const int lane = tid & 63;

    fvec4 acc[EE_K];
    #pragma unroll
    for (int k = 0; k < EE_K; ++k) acc[k] = (fvec4)0.f;

    for (int base = wave * 64; base < na; base += 256) {
        int a = base + lane;
        int s = -1, id = 0;
        if (a < na) { s = segs[a]; id = ids[a]; }        // coalesced 256B loads
        #pragma unroll
        for (int k = 0; k < EE_K; ++k) {
            unsigned long long m = __ballot(s == t0 + k);
            while (m) {                                  // ~0.06 matches/type/iter
                int j = __ffsll((long long)m) - 1;
                m &= m - 1;
                int aid = __shfl(id, j);
                acc[k] += attr[(size_t)aid * EE_D4 + lane];  // 1KB coalesced row
            }
        }
    }

    __shared__ fvec4 red[EE_K][4][64];
    #pragma unroll
    for (int k = 0; k < EE_K; ++k) red[k][wave][lane] = acc[k];
    __syncthreads();
    if (wave < EE_K) {                                   // wave k finalizes type t0+k
        int k = wave;
        fvec4 r = red[k][0][lane];
        #pragma unroll
        for (int w = 1; w < 4; ++w) r += red[k][w][lane];
        r += ete[(size_t)(t0 + k) * EE_D4 + lane];
        comb[(size_t)(t0 + k) * EE_D4 + lane] = r;
    }
}

// Phase B: out[r][:] = comb[data[r]][:]. Each wave: one coalesced NT load of 64
// indices, then 64 fully-unrolled (readlane -> L2 comb load -> 1KB NT store).
__global__ __launch_bounds__(256) void ee_gather_out(
        const int* __restrict__ data,
        const fvec4* __restrict__ comb,
        fvec4* __restrict__ out, int n) {
    const int gid  = blockIdx.x * blockDim.x + threadIdx.x;
    const int wave = gid >> 6;
    const int lane = gid & 63;
    const int nw   = (gridDim.x * blockDim.x) >> 6;

    for (int base = wave * 64; base < n; base += nw * 64) {
        int r = base + lane;
        int idx = (r < n) ? __builtin_nontemporal_load(&data[r]) : 0;
        int lim = n - base;
        if (lim >= 64) {
            #pragma unroll                               // j compile-time -> v_readlane
            for (int j = 0; j < 64; ++j) {
                int t = __builtin_amdgcn_readlane(idx, j);
                fvec4 v = comb[(size_t)t * EE_D4 + lane];
                __builtin_nontemporal_store(v, &out[(size_t)(base + j) * EE_D4 + lane]);
            }
        } else {
            for (int j = 0; j < lim; ++j) {
                int t = __shfl(idx, j);
                fvec4 v = comb[(size_t)t * EE_D4 + lane];
                __builtin_nontemporal_store(v, &out[(size_t)(base + j) * EE_D4 + lane]);
            }
        }
    }
}

extern "C" void kernel_launch(void* const* d_in, const int* in_sizes, int n_in,
                              void* d_out, int out_size, void* d_ws, size_t ws_size,
                              hipStream_t stream) {
    const int*   data          = (const int*)d_in[0];
    const float* attr_table    = (const float*)d_in[1];
    const float* ete           = (const float*)d_in[2];
    const int*   flat_attr_ids = (const int*)d_in[3];
    const int*   attr_seg_ids  = (const int*)d_in[4];
    fvec4* comb = (fvec4*)d_ws;                    // 1000*256 f32 = 1 MB scratch
    int N  = in_sizes[0];                          // 1,000,000 edges
    int TA = in_sizes[3];                          // 50,000 ragged attrs

    ee_build_comb<<<EE_NT / EE_K, 256, 0, stream>>>(
        (const fvec4*)ete, (const fvec4*)attr_table,
        flat_attr_ids, attr_seg_ids, comb, TA);

    ee_gather_out<<<2048, 256, 0, stream>>>(
        data, comb, (fvec4*)d_out, N);
}